// Round 2
// baseline (204.242 us; speedup 1.0000x reference)
//
#include <hip/hip_runtime.h>
#include <math.h>

#define N_POS 8000
#define C_CH  128
#define KSPLIT 5
#define KT_PER 25      // 125 k-tiles of 64 keys, 25 per split
#define QTILES 125     // q-tiles of 64 queries

typedef __bf16 bf16x8 __attribute__((ext_vector_type(8)));
typedef float  f32x4  __attribute__((ext_vector_type(4)));

#define MFMA(a,b,c) __builtin_amdgcn_mfma_f32_16x16x32_bf16((a),(b),(c),0,0,0)

// MFMA 16x16x32 lane layouts (verified m89/m120):
//   A[m][k]: m = lane&15, k = (lane>>4)*8 + j
//   B[k][n]: n = lane&15, k = (lane>>4)*8 + j
//   D[m][n]: n = lane&15, m = (lane>>4)*4 + reg

// ---------------------------------------------------------------------------
// Kernel A: QKV projections via MFMA. grid 250 (n-tiles of 32), block 256.
// out rows: o 0..15 -> q, 16..31 -> k, 32..159 -> v(ch=o-32)
// q_bf,k_bf: [n][16] bf16.  v_bf: [c][8000] bf16.
// ---------------------------------------------------------------------------
__global__ __launch_bounds__(256) void qkv_kernel(
    const float* __restrict__ x,
    const float* __restrict__ wq, const float* __restrict__ bq,
    const float* __restrict__ wk, const float* __restrict__ bk,
    const float* __restrict__ wv, const float* __restrict__ bv,
    __bf16* __restrict__ q_bf, __bf16* __restrict__ k_bf, __bf16* __restrict__ v_bf)
{
    __shared__ __bf16 x_lds[32 * 136];          // [n][c]
    __shared__ __bf16 v_out[128 * 36];          // [ch][n]

    const int t    = threadIdx.x;
    const int n0   = blockIdx.x * 32;
    const int lane = t & 63;
    const int w    = t >> 6;
    const int l15  = lane & 15;
    const int quad = lane >> 4;

    // stage x tile [128c x 32n] -> x_lds[n][c] bf16 (transpose+convert)
    for (int r = 0; r < 4; ++r) {
        int f = r * 256 + t;
        int ch = f >> 3, n4 = f & 7;
        float4 xv = *reinterpret_cast<const float4*>(&x[ch * N_POS + n0 + n4 * 4]);
        x_lds[(n4 * 4 + 0) * 136 + ch] = (__bf16)xv.x;
        x_lds[(n4 * 4 + 1) * 136 + ch] = (__bf16)xv.y;
        x_lds[(n4 * 4 + 2) * 136 + ch] = (__bf16)xv.z;
        x_lds[(n4 * 4 + 3) * 136 + ch] = (__bf16)xv.w;
    }

    // A-frags: weight rows fp32->bf16 in regs. wave w owns mtiles {w, w+4, w+8<10}
    bf16x8 aw[3][4];
    f32x4  acc[3][2];
    const int nmt = (w < 2) ? 3 : 2;
    for (int mi = 0; mi < nmt; ++mi) {
        int mt = w + 4 * mi;
        const float *wrow, *brow;
        if (mt == 0)      { wrow = wq + l15 * 128;               brow = bq; }
        else if (mt == 1) { wrow = wk + l15 * 128;               brow = bk; }
        else              { wrow = wv + ((mt - 2) * 16 + l15) * 128;
                            brow = bv + (mt - 2) * 16; }
        for (int ks = 0; ks < 4; ++ks) {
            float4 f0 = *reinterpret_cast<const float4*>(wrow + ks * 32 + quad * 8);
            float4 f1 = *reinterpret_cast<const float4*>(wrow + ks * 32 + quad * 8 + 4);
            bf16x8 a;
            a[0]=(__bf16)f0.x; a[1]=(__bf16)f0.y; a[2]=(__bf16)f0.z; a[3]=(__bf16)f0.w;
            a[4]=(__bf16)f1.x; a[5]=(__bf16)f1.y; a[6]=(__bf16)f1.z; a[7]=(__bf16)f1.w;
            aw[mi][ks] = a;
        }
        for (int ni = 0; ni < 2; ++ni) {
            acc[mi][ni][0] = brow[quad * 4 + 0]; acc[mi][ni][1] = brow[quad * 4 + 1];
            acc[mi][ni][2] = brow[quad * 4 + 2]; acc[mi][ni][3] = brow[quad * 4 + 3];
        }
    }
    __syncthreads();

    for (int ks = 0; ks < 4; ++ks) {
        bf16x8 b0 = *reinterpret_cast<const bf16x8*>(&x_lds[(0  + l15) * 136 + ks * 32 + quad * 8]);
        bf16x8 b1 = *reinterpret_cast<const bf16x8*>(&x_lds[(16 + l15) * 136 + ks * 32 + quad * 8]);
        for (int mi = 0; mi < nmt; ++mi) {
            acc[mi][0] = MFMA(aw[mi][ks], b0, acc[mi][0]);
            acc[mi][1] = MFMA(aw[mi][ks], b1, acc[mi][1]);
        }
    }

    union S4 { short4 s; __bf16 b[4]; };
    for (int mi = 0; mi < nmt; ++mi) {
        int mt = w + 4 * mi;
        for (int ni = 0; ni < 2; ++ni) {
            S4 u;
            u.b[0]=(__bf16)acc[mi][ni][0]; u.b[1]=(__bf16)acc[mi][ni][1];
            u.b[2]=(__bf16)acc[mi][ni][2]; u.b[3]=(__bf16)acc[mi][ni][3];
            int n = n0 + ni * 16 + l15;
            if (mt == 0) {
                *reinterpret_cast<short4*>(&q_bf[n * 16 + quad * 4]) = u.s;
            } else if (mt == 1) {
                *reinterpret_cast<short4*>(&k_bf[n * 16 + quad * 4]) = u.s;
            } else {
                int ch0 = (mt - 2) * 16 + quad * 4;
                int nl  = ni * 16 + l15;
                v_out[(ch0 + 0) * 36 + nl] = u.b[0];
                v_out[(ch0 + 1) * 36 + nl] = u.b[1];
                v_out[(ch0 + 2) * 36 + nl] = u.b[2];
                v_out[(ch0 + 3) * 36 + nl] = u.b[3];
            }
        }
    }
    __syncthreads();
    for (int r = 0; r < 4; ++r) {
        int f = r * 256 + t;
        int ch = f >> 3, n4 = f & 7;
        int2 d = *reinterpret_cast<const int2*>(&v_out[ch * 36 + n4 * 4]);
        *reinterpret_cast<int2*>(&v_bf[ch * N_POS + n0 + n4 * 4]) = d;
    }
}

// ---------------------------------------------------------------------------
// Kernel B v3: fused attention, split-K. V and K go GLOBAL->REGISTERS
// directly (A-fragment of 16x16x32 is 16B contiguous per lane in v_bf[c][n]
// row-major); only P transits LDS (cross-wave key exchange), double-buffered
// + XOR-swizzled. One __syncthreads per k-tile. No global_load_lds DMA.
//
// Per iteration (tile kt):
//   1. issue V(kt) loads (8 b128/wave) + K(kt+1) load (1 b128, quad<2)
//   2. S: 4 MFMA (K(kt) regs x Q regs) -> exp -> bf16 -> ds_write P[kt&1]
//      (l-sum: shuffle-reduce the quantized bf16 P over quads, accum in regs)
//   3. __syncthreads  (drains V(kt)/K(kt+1) with S-phase cover; P visible)
//   4. PV: wave (wc=w>>1 ch-half, wq=w&1 q-half): 16 MFMA from V regs x
//      P LDS reads (4 b128/wave, conflict-free via slot^(qrow&7) swizzle)
//
// P LDS layout: row q (128 B), key-slot s (16 B) stored at slot s^(q&7).
//   writer: key-byte (w*32+quad*8), qrow ni*16+l15  -> b64, 4-way conflict max
//   reader: key-byte (ks*64+quad*16), qrow .. +l15  -> b128, conflict-free
// ---------------------------------------------------------------------------
__global__ __launch_bounds__(256, 3) void attn_kernel(
    const __bf16* __restrict__ q_bf, const __bf16* __restrict__ k_bf,
    const __bf16* __restrict__ v_bf, float* __restrict__ av_part,
    float* __restrict__ l_part)
{
    __shared__ __bf16 p_lds[2][4096];   // 2 x 8 KB

    const int t    = threadIdx.x;
    const int qt   = blockIdx.x % QTILES;
    const int sp   = blockIdx.x / QTILES;
    const int n0q  = qt * 64;
    const int lane = t & 63;
    const int w    = t >> 6;
    const int l15  = lane & 15;
    const int quad = lane >> 4;
    const int wc   = w >> 1;     // ch half (64 ch)
    const int wq   = w & 1;      // q half (32 q)

    // Q B-frags in registers (k-dim 16 padded to 32 with zeros), 4 q-groups
    bf16x8 aq[4];
    for (int ni = 0; ni < 4; ++ni) {
        for (int j = 0; j < 8; ++j) aq[ni][j] = (__bf16)0.0f;
        if (quad < 2)
            aq[ni] = *reinterpret_cast<const bf16x8*>(
                &q_bf[(n0q + ni * 16 + l15) * 16 + quad * 8]);
    }

    f32x4 acc[4][2];                    // [ct][qi]
    for (int ct = 0; ct < 4; ++ct)
        for (int qi = 0; qi < 2; ++qi)
            for (int r = 0; r < 4; ++r) acc[ct][qi][r] = 0.f;
    float lp[4] = {0.f, 0.f, 0.f, 0.f};

    const int kt0  = sp * KT_PER;
    const int ktEnd = kt0 + KT_PER;

    // V per-lane base: row ch = wc*64 + ct*16 + l15, col offset quad*8
    const __bf16* vbase = v_bf + (wc * 64 + l15) * N_POS + quad * 8;

    // P write byte offset (per ni add ni*2048):
    const int pw_off = l15 * 128 + (((w * 2 + (quad >> 1)) ^ (l15 & 7)) * 16)
                     + (quad & 1) * 8;
    // P read byte offsets [qi][ks]:
    int pr_off[2][2];
    for (int qi = 0; qi < 2; ++qi)
        for (int ks = 0; ks < 2; ++ks)
            pr_off[qi][ks] = (wq * 32 + qi * 16 + l15) * 128
                           + (((ks * 4 + quad) ^ (l15 & 7)) * 16);

    union S4 { short4 sh; __bf16 b[4]; };

    // K prologue load (double-buffered regs kA/kB, zero-padded upper k-half)
    bf16x8 kA, kB;
    for (int j = 0; j < 8; ++j) { kA[j] = (__bf16)0.0f; kB[j] = (__bf16)0.0f; }
    if (quad < 2)
        kA = *reinterpret_cast<const bf16x8*>(
            &k_bf[(kt0 * 64 + w * 16 + l15) * 16 + quad * 8]);

    auto iter = [&](int kt, bf16x8& kc, bf16x8& kn, int pbuf) {
        const int n0k = kt * 64;
        // 1. V(kt) global->reg (consumed after the barrier; S-phase = cover)
        bf16x8 vf[4][2];
#pragma unroll
        for (int ct = 0; ct < 4; ++ct)
#pragma unroll
            for (int ks = 0; ks < 2; ++ks)
                vf[ct][ks] = *reinterpret_cast<const bf16x8*>(
                    vbase + ct * (16 * N_POS) + n0k + ks * 32);
        // K(kt+1) prefetch
        if (kt + 1 < ktEnd) {
            if (quad < 2)
                kn = *reinterpret_cast<const bf16x8*>(
                    &k_bf[((n0k + 64) + w * 16 + l15) * 16 + quad * 8]);
        }

        // 2. S phase: wave w owns keys w*16..+15, all 64 q
        char* pb = reinterpret_cast<char*>(&p_lds[pbuf][0]);
#pragma unroll
        for (int ni = 0; ni < 4; ++ni) {
            f32x4 s;
            for (int r = 0; r < 4; ++r) s[r] = 0.f;
            s = MFMA(kc, aq[ni], s);       // D[m=key][n=q]
            S4 u;
            u.b[0] = (__bf16)__expf(s[0]); u.b[1] = (__bf16)__expf(s[1]);
            u.b[2] = (__bf16)__expf(s[2]); u.b[3] = (__bf16)__expf(s[3]);
            *reinterpret_cast<short4*>(pb + pw_off + ni * 2048) = u.sh;
            // l partial: sum the QUANTIZED p over this wave's 16 keys
            float ps = (float)u.b[0] + (float)u.b[1]
                     + (float)u.b[2] + (float)u.b[3];
            ps += __shfl_xor(ps, 16, 64);
            ps += __shfl_xor(ps, 32, 64);
            lp[ni] += ps;
        }

        __syncthreads();   // P[pbuf] visible; V(kt)/K(kt+1) drained (S cover)

        // 4. PV: A = V regs, B = P LDS
        const char* pr = reinterpret_cast<const char*>(&p_lds[pbuf][0]);
#pragma unroll
        for (int ks = 0; ks < 2; ++ks) {
            bf16x8 p0 = *reinterpret_cast<const bf16x8*>(pr + pr_off[0][ks]);
            bf16x8 p1 = *reinterpret_cast<const bf16x8*>(pr + pr_off[1][ks]);
#pragma unroll
            for (int ct = 0; ct < 4; ++ct) {
                acc[ct][0] = MFMA(vf[ct][ks], p0, acc[ct][0]);
                acc[ct][1] = MFMA(vf[ct][ks], p1, acc[ct][1]);
            }
        }
    };

    for (int i = 0; i < KT_PER; i += 2) {
        iter(kt0 + i, kA, kB, 0);
        if (i + 1 < KT_PER) iter(kt0 + i + 1, kB, kA, 1);
    }

    // epilogue: cross-wave l reduction via LDS (reuse p_lds[0] as f32 scratch)
    __syncthreads();
    float* lsh = reinterpret_cast<float*>(&p_lds[0][0]);   // 256 floats
    if (quad == 0) {
#pragma unroll
        for (int ni = 0; ni < 4; ++ni)
            lsh[w * 64 + ni * 16 + l15] = lp[ni];
    }
    __syncthreads();

    // av partials: av_part[sp][n][c] fp32
    float* dst = av_part + (size_t)sp * 1024000;
#pragma unroll
    for (int ct = 0; ct < 4; ++ct)
#pragma unroll
        for (int qi = 0; qi < 2; ++qi) {
            int n  = n0q + wq * 32 + qi * 16 + l15;
            int ch = wc * 64 + ct * 16 + quad * 4;
            *reinterpret_cast<f32x4*>(&dst[n * 128 + ch]) = acc[ct][qi];
        }
    if (t < 64)
        l_part[sp * N_POS + n0q + t] =
            lsh[t] + lsh[64 + t] + lsh[128 + t] + lsh[192 + t];
}

// ---------------------------------------------------------------------------
// Kernel C: split-K reduce + normalize (fp32, in LDS) fused with
// y = wa @ av + ba (MFMA) + BN stats.  grid 250 (B tile built ONCE per block;
// each wave owns 2 mtiles).
// ---------------------------------------------------------------------------
__global__ __launch_bounds__(256) void proj_out_kernel(
    const float* __restrict__ av_part, const float* __restrict__ l_part,
    const float* __restrict__ wa, const float* __restrict__ ba,
    float* __restrict__ y_ws, float* __restrict__ bn_sum, float* __restrict__ bn_sumsq)
{
    __shared__ __bf16 b_lds[4096];   // 32n x 128c fragment-packed, swizzled

    const int t    = threadIdx.x;
    const int n0   = blockIdx.x * 32;
    const int lane = t & 63;
    const int w    = t >> 6;
    const int l15  = lane & 15;
    const int quad = lane >> 4;

    // build normalized B tile: 512 c-octets, 2 per thread (coalesced reads)
    for (int r = 0; r < 2; ++r) {
        int g = r * 256 + t;
        int n = g >> 4, oc = g & 15;
        float l = 0.f;
#pragma unroll
        for (int s = 0; s < KSPLIT; ++s) l += l_part[s * N_POS + n0 + n];
        float4 a0 = make_float4(0.f, 0.f, 0.f, 0.f);
        float4 a1 = make_float4(0.f, 0.f, 0.f, 0.f);
#pragma unroll
        for (int s = 0; s < KSPLIT; ++s) {
            const float* p = av_part + (size_t)s * 1024000 + (n0 + n) * 128 + oc * 8;
            float4 u = *reinterpret_cast<const float4*>(p);
            float4 v = *reinterpret_cast<const float4*>(p + 4);
            a0.x += u.x; a0.y += u.y; a0.z += u.z; a0.w += u.w;
            a1.x += v.x; a1.y += v.y; a1.z += v.z; a1.w += v.w;
        }
        float inv = 1.f / l;
        union { int4 iv; __bf16 b[8]; } u;
        u.b[0]=(__bf16)(a0.x*inv); u.b[1]=(__bf16)(a0.y*inv);
        u.b[2]=(__bf16)(a0.z*inv); u.b[3]=(__bf16)(a0.w*inv);
        u.b[4]=(__bf16)(a1.x*inv); u.b[5]=(__bf16)(a1.y*inv);
        u.b[6]=(__bf16)(a1.z*inv); u.b[7]=(__bf16)(a1.w*inv);
        int A = (n >> 4) * 16 + oc;
        int slot = (n & 15) ^ (oc & 7);
        *reinterpret_cast<int4*>(&b_lds[(A * 16 + slot) * 8]) = u.iv;
    }

    // A-frags: wa rows for mtiles {2w, 2w+1}
    bf16x8 aw[2][4];
    f32x4  acc[2][2];
    for (int mi = 0; mi < 2; ++mi) {
        int mt = 2 * w + mi;
        const float* wrow = wa + (mt * 16 + l15) * 128;
        for (int ks = 0; ks < 4; ++ks) {
            float4 f0 = *reinterpret_cast<const float4*>(wrow + ks * 32 + quad * 8);
            float4 f1 = *reinterpret_cast<const float4*>(wrow + ks * 32 + quad * 8 + 4);
            bf16x8 a;
            a[0]=(__bf16)f0.x; a[1]=(__bf16)f0.y; a[2]=(__bf16)f0.z; a[3]=(__bf16)f0.w;
            a[4]=(__bf16)f1.x; a[5]=(__bf16)f1.y; a[6]=(__bf16)f1.z; a[7]=(__bf16)f1.w;
            aw[mi][ks] = a;
        }
        for (int ni = 0; ni < 2; ++ni) {
            acc[mi][ni][0] = ba[mt * 16 + quad * 4 + 0];
            acc[mi][ni][1] = ba[mt * 16 + quad * 4 + 1];
            acc[mi][ni][2] = ba[mt * 16 + quad * 4 + 2];
            acc[mi][ni][3] = ba[mt * 16 + quad * 4 + 3];
        }
    }
    __syncthreads();

    for (int ks = 0; ks < 4; ++ks) {
        int oc = ks * 4 + quad;
        int slot = l15 ^ (oc & 7);
        bf16x8 b0 = *reinterpret_cast<const bf16x8*>(&b_lds[((0  + oc) * 16 + slot) * 8]);
        bf16x8 b1 = *reinterpret_cast<const bf16x8*>(&b_lds[((16 + oc) * 16 + slot) * 8]);
        for (int mi = 0; mi < 2; ++mi) {
            acc[mi][0] = MFMA(aw[mi][ks], b0, acc[mi][0]);
            acc[mi][1] = MFMA(aw[mi][ks], b1, acc[mi][1]);
        }
    }

    // y writes [c][n] + BN partial stats
    for (int mi = 0; mi < 2; ++mi) {
        for (int r = 0; r < 4; ++r) {
            int ch = (2 * w + mi) * 16 + quad * 4 + r;
            float v0 = acc[mi][0][r];
            float v1 = acc[mi][1][r];
            y_ws[ch * N_POS + n0 + 0  + l15] = v0;
            y_ws[ch * N_POS + n0 + 16 + l15] = v1;
            float s1 = v0 + v1;
            float s2 = v0 * v0 + v1 * v1;
#pragma unroll
            for (int off = 8; off >= 1; off >>= 1) {
                s1 += __shfl_xor(s1, off, 64);
                s2 += __shfl_xor(s2, off, 64);
            }
            if (l15 == 0) {
                atomicAdd(&bn_sum[ch],   s1);
                atomicAdd(&bn_sumsq[ch], s2);
            }
        }
    }
}

// ---------------------------------------------------------------------------
// Kernel D: BatchNorm (training stats) + ReLU + residual. grid 1000, block 256.
// ---------------------------------------------------------------------------
__global__ __launch_bounds__(256) void bn_relu_kernel(
    const float* __restrict__ y_ws, const float* __restrict__ x,
    const float* __restrict__ bn_sum, const float* __restrict__ bn_sumsq,
    const float* __restrict__ bn_w, const float* __restrict__ bn_b,
    float* __restrict__ out)
{
    const int i4 = blockIdx.x * 256 + threadIdx.x;
    const int c  = i4 / 2000;
    const float mean  = bn_sum[c]   * (1.f / 8000.f);
    const float var   = bn_sumsq[c] * (1.f / 8000.f) - mean * mean;
    const float rstd  = rsqrtf(var + 1e-5f);
    const float scale = bn_w[c] * rstd;
    const float shift = bn_b[c] - mean * scale;

    float4 y4 = reinterpret_cast<const float4*>(y_ws)[i4];
    float4 x4 = reinterpret_cast<const float4*>(x)[i4];
    float4 o4;
    o4.x = fmaxf(y4.x * scale + shift, 0.f) + x4.x;
    o4.y = fmaxf(y4.y * scale + shift, 0.f) + x4.y;
    o4.z = fmaxf(y4.z * scale + shift, 0.f) + x4.z;
    o4.w = fmaxf(y4.w * scale + shift, 0.f) + x4.w;
    reinterpret_cast<float4*>(out)[i4] = o4;
}

// ---------------------------------------------------------------------------
extern "C" void kernel_launch(void* const* d_in, const int* in_sizes, int n_in,
                              void* d_out, int out_size, void* d_ws, size_t ws_size,
                              hipStream_t stream)
{
    const float* x    = (const float*)d_in[0];
    const float* wq   = (const float*)d_in[1];
    const float* bq   = (const float*)d_in[2];
    const float* wk   = (const float*)d_in[3];
    const float* bk   = (const float*)d_in[4];
    const float* wv   = (const float*)d_in[5];
    const float* bv   = (const float*)d_in[6];
    const float* wa   = (const float*)d_in[7];
    const float* ba   = (const float*)d_in[8];
    const float* bn_w = (const float*)d_in[9];
    const float* bn_b = (const float*)d_in[10];
    float* out = (float*)d_out;

    char* base = (char*)d_ws;
    // byte layout (~27.3 MB):
    float*  av_part = (float*)base;                    // 20,480,000 B (5 x 8000 x 128 f32)
    __bf16* q_bf    = (__bf16*)(base + 20480000);      //    256,000 B
    __bf16* k_bf    = (__bf16*)(base + 20736000);      //    256,000 B
    __bf16* v_bf    = (__bf16*)(base + 20992000);      //  2,048,000 B
    float*  l_part  = (float*)(base + 23040000);       //    160,000 B
    float*  bn_sum   = (float*)(base + 23200000);      //        512 B
    float*  bn_sumsq = bn_sum + 128;                   //        512 B
    float*  y_ws    = (float*)(base + 23201024);       //  4,096,000 B

    hipMemsetAsync(bn_sum, 0, 1024, stream);
    qkv_kernel<<<250, 256, 0, stream>>>(x, wq, bq, wk, bk, wv, bv, q_bf, k_bf, v_bf);
    attn_kernel<<<QTILES * KSPLIT, 256, 0, stream>>>(q_bf, k_bf, v_bf, av_part, l_part);
    proj_out_kernel<<<250, 256, 0, stream>>>(av_part, l_part, wa, ba, y_ws, bn_sum, bn_sumsq);
    bn_relu_kernel<<<1000, 256, 0, stream>>>(y_ws, x, bn_sum, bn_sumsq, bn_w, bn_b, out);
}

// Round 3
// 189.398 us; speedup vs baseline: 1.0784x; 1.0784x over previous
//
#include <hip/hip_runtime.h>
#include <math.h>

#define N_POS 8000
#define C_CH  128
#define KSPLIT 5
#define KT_PER 25      // 125 k-tiles of 64 keys, 25 per split
#define QTILES 125     // q-tiles of 64 queries

typedef __bf16 bf16x8 __attribute__((ext_vector_type(8)));
typedef float  f32x4  __attribute__((ext_vector_type(4)));

#define MFMA(a,b,c) __builtin_amdgcn_mfma_f32_16x16x32_bf16((a),(b),(c),0,0,0)

// MFMA 16x16x32 lane layouts (verified m89/m120):
//   A[m][k]: m = lane&15, k = (lane>>4)*8 + j
//   B[k][n]: n = lane&15, k = (lane>>4)*8 + j
//   D[m][n]: n = lane&15, m = (lane>>4)*4 + reg

#define GLOAD_LDS(gp, lp) \
    __builtin_amdgcn_global_load_lds( \
        (const __attribute__((address_space(1))) void*)(gp), \
        (__attribute__((address_space(3))) void*)(lp), 16, 0, 0)

// ---------------------------------------------------------------------------
// Kernel A: QKV projections via MFMA. grid 500 (n-tiles of 16), block 256.
// v4: n-tile 32->16 so grid 250->500 -> 2 blocks/CU (latency hiding; the
// kernel was 1-block/CU occupancy-starved).
// out rows: o 0..15 -> q, 16..31 -> k, 32..159 -> v(ch=o-32)
// q_bf,k_bf: [n][16] bf16.  v_bf: [c][8000] bf16.
// ---------------------------------------------------------------------------
__global__ __launch_bounds__(256) void qkv_kernel(
    const float* __restrict__ x,
    const float* __restrict__ wq, const float* __restrict__ bq,
    const float* __restrict__ wk, const float* __restrict__ bk,
    const float* __restrict__ wv, const float* __restrict__ bv,
    __bf16* __restrict__ q_bf, __bf16* __restrict__ k_bf, __bf16* __restrict__ v_bf)
{
    __shared__ __bf16 x_lds[16 * 136];          // [n][c]
    __shared__ __bf16 v_out[128 * 20];          // [ch][n] stride 20 (40B, int2-aligned)

    const int t    = threadIdx.x;
    const int n0   = blockIdx.x * 16;
    const int lane = t & 63;
    const int w    = t >> 6;
    const int l15  = lane & 15;
    const int quad = lane >> 4;

    // stage x tile [128c x 16n] -> x_lds[n][c] bf16 (transpose+convert)
    for (int r = 0; r < 2; ++r) {
        int f = r * 256 + t;                    // 0..511
        int ch = f >> 2, n4 = f & 3;
        float4 xv = *reinterpret_cast<const float4*>(&x[ch * N_POS + n0 + n4 * 4]);
        x_lds[(n4 * 4 + 0) * 136 + ch] = (__bf16)xv.x;
        x_lds[(n4 * 4 + 1) * 136 + ch] = (__bf16)xv.y;
        x_lds[(n4 * 4 + 2) * 136 + ch] = (__bf16)xv.z;
        x_lds[(n4 * 4 + 3) * 136 + ch] = (__bf16)xv.w;
    }

    // A-frags: weight rows fp32->bf16 in regs. wave w owns mtiles {w, w+4, w+8<10}
    bf16x8 aw[3][4];
    f32x4  acc[3];
    const int nmt = (w < 2) ? 3 : 2;
    for (int mi = 0; mi < nmt; ++mi) {
        int mt = w + 4 * mi;
        const float *wrow, *brow;
        if (mt == 0)      { wrow = wq + l15 * 128;               brow = bq; }
        else if (mt == 1) { wrow = wk + l15 * 128;               brow = bk; }
        else              { wrow = wv + ((mt - 2) * 16 + l15) * 128;
                            brow = bv + (mt - 2) * 16; }
        for (int ks = 0; ks < 4; ++ks) {
            float4 f0 = *reinterpret_cast<const float4*>(wrow + ks * 32 + quad * 8);
            float4 f1 = *reinterpret_cast<const float4*>(wrow + ks * 32 + quad * 8 + 4);
            bf16x8 a;
            a[0]=(__bf16)f0.x; a[1]=(__bf16)f0.y; a[2]=(__bf16)f0.z; a[3]=(__bf16)f0.w;
            a[4]=(__bf16)f1.x; a[5]=(__bf16)f1.y; a[6]=(__bf16)f1.z; a[7]=(__bf16)f1.w;
            aw[mi][ks] = a;
        }
        acc[mi][0] = brow[quad * 4 + 0]; acc[mi][1] = brow[quad * 4 + 1];
        acc[mi][2] = brow[quad * 4 + 2]; acc[mi][3] = brow[quad * 4 + 3];
    }
    __syncthreads();

    for (int ks = 0; ks < 4; ++ks) {
        bf16x8 b0 = *reinterpret_cast<const bf16x8*>(&x_lds[l15 * 136 + ks * 32 + quad * 8]);
        for (int mi = 0; mi < nmt; ++mi)
            acc[mi] = MFMA(aw[mi][ks], b0, acc[mi]);
    }

    union S4 { short4 s; __bf16 b[4]; };
    for (int mi = 0; mi < nmt; ++mi) {
        int mt = w + 4 * mi;
        S4 u;
        u.b[0]=(__bf16)acc[mi][0]; u.b[1]=(__bf16)acc[mi][1];
        u.b[2]=(__bf16)acc[mi][2]; u.b[3]=(__bf16)acc[mi][3];
        int n = n0 + l15;
        if (mt == 0) {
            *reinterpret_cast<short4*>(&q_bf[n * 16 + quad * 4]) = u.s;
        } else if (mt == 1) {
            *reinterpret_cast<short4*>(&k_bf[n * 16 + quad * 4]) = u.s;
        } else {
            int ch0 = (mt - 2) * 16 + quad * 4;
            v_out[(ch0 + 0) * 20 + l15] = u.b[0];
            v_out[(ch0 + 1) * 20 + l15] = u.b[1];
            v_out[(ch0 + 2) * 20 + l15] = u.b[2];
            v_out[(ch0 + 3) * 20 + l15] = u.b[3];
        }
    }
    __syncthreads();
    for (int r = 0; r < 2; ++r) {
        int f = r * 256 + t;                    // 0..511
        int ch = f >> 2, n4 = f & 3;
        int2 d = *reinterpret_cast<const int2*>(&v_out[ch * 20 + n4 * 4]);
        *reinterpret_cast<int2*>(&v_bf[ch * N_POS + n0 + n4 * 4]) = d;
    }
}

// ---------------------------------------------------------------------------
// Kernel B: fused attention, split-K, MFMA, global_load_lds double-buffer.
// (round-1 version, verified ~39 us: q-tile 64, stage-early + non-draining
// barrier_B so next-tile DMA stays in flight across the whole S+PV body.
// v3's global->reg V was a regression: lane-major row addressing = 64
// distinct cache lines per VMEM instr, TA-serialized.)
//
// Per iter:
//   __syncthreads (barrier_A, vmcnt(0)): tile-kt DMA drained -- issued a FULL
//     iteration ago, so the drain is cheap; prev PV LDS reads done.
//   issue tile kt+1 DMA into buf^1 (safe: buf^1 last read before barrier_A)
//   S phase: S = K^T Q (K=16 padded to 32), exp -> p_lds (chunked layout)
//   s_waitcnt lgkmcnt(0) + raw s_barrier (barrier_B): P visible, DMA in flight
//   PV phase: acc += V * P   (XOR-swizzled V chunks, conflict-free b128 reads)
//
// LDS chunk maps (lane-sequential DMA dests, conflict-free fragment reads):
//   V chunk(ch,part) at ((ch>>3)*64 + (ch&7)*8 + (part^(ch&7)))*16B
//   K [key][dim16] contiguous (32B/key); upper k-half of A-frag zero in regs
//   P chunk(q,octet) at (octet*64 + q)*16B   (octet = key>>3, q = 0..63)
// ---------------------------------------------------------------------------
__global__ __launch_bounds__(256, 3) void attn_kernel(
    const __bf16* __restrict__ q_bf, const __bf16* __restrict__ k_bf,
    const __bf16* __restrict__ v_bf, float* __restrict__ av_part,
    float* __restrict__ l_part)
{
    __shared__ __bf16 v_buf[2][8192];   // 16 KB each
    __shared__ __bf16 k_buf[2][1024];   // 2 KB each
    __shared__ __bf16 p_lds[4096];      // 8 KB (64 keys x 64 queries); total 45056 B -> 3 blocks/CU

    const int t    = threadIdx.x;
    const int qt   = blockIdx.x % QTILES;
    const int sp   = blockIdx.x / QTILES;
    const int n0q  = qt * 64;
    const int lane = t & 63;
    const int w    = t >> 6;
    const int l15  = lane & 15;
    const int quad = lane >> 4;

    // staging maps (per lane, loop-invariant)
    const int chL   = lane >> 3;              // V: low 3 bits of channel
    const int vpart = (lane & 7) ^ chL;       // V: key-octet (XOR swizzle)
    const int kkey  = lane >> 1;              // K: key within 32-key half
    const int khalf = lane & 1;               // K: dim half

    // Q B-frags in registers (k-dim 16 padded to 32 with zeros), 4 q-groups
    bf16x8 aq[4];
    for (int ni = 0; ni < 4; ++ni) {
        for (int j = 0; j < 8; ++j) aq[ni][j] = (__bf16)0.0f;
        if (quad < 2)
            aq[ni] = *reinterpret_cast<const bf16x8*>(
                &q_bf[(n0q + ni * 16 + l15) * 16 + quad * 8]);
    }
    bf16x8 ones;
    for (int j = 0; j < 8; ++j) ones[j] = (__bf16)1.0f;

    f32x4 acc[2][4];
    for (int mi = 0; mi < 2; ++mi)
        for (int ni = 0; ni < 4; ++ni)
            for (int r = 0; r < 4; ++r) acc[mi][ni][r] = 0.f;
    f32x4 lacc;
    for (int r = 0; r < 4; ++r) lacc[r] = 0.f;

    const int kt0 = sp * KT_PER;

    // issue one tile's staging DMA: 4 V ops per wave; K ops on waves 0,1 only
    // (vmcnt non-uniform is fine: barrier_A drains with vmcnt(0))
    auto stage = [&](int kt, int buf) {
        const int n0k = kt * 64;
        for (int r = 0; r < 4; ++r) {
            int R = w * 4 + r;   // wave-uniform LDS base
            GLOAD_LDS(v_bf + (8 * R + chL) * N_POS + n0k + vpart * 8,
                      &v_buf[buf][R * 512]);
        }
        if (w < 2)
            GLOAD_LDS(k_bf + (size_t)(n0k + w * 32 + kkey) * 16 + khalf * 8,
                      &k_buf[buf][w * 512]);
    };

    stage(kt0, 0);

    const int oS  = w * 2 + (quad >> 1);   // P-write octet
    const int sub = (quad & 1) * 4;        // P-write elem offset in chunk

    union S4 { short4 sh; __bf16 b[4]; };

    for (int kt = kt0; kt < kt0 + KT_PER; ++kt) {
        const int cur = (kt - kt0) & 1;
        __syncthreads();   // barrier_A: vmcnt(0) drain of tile-kt DMA (1 iter of cover)

        // issue next tile's DMA NOW -> in flight across S + barrier_B + PV
        if (kt + 1 < kt0 + KT_PER) stage(kt + 1, cur ^ 1);

        // ---- S phase: A = K rows (wave w -> keys w*16..+15), B = Q regs
        bf16x8 ak;
        for (int j = 0; j < 8; ++j) ak[j] = (__bf16)0.0f;
        if (quad < 2)
            ak = *reinterpret_cast<const bf16x8*>(
                &k_buf[cur][(w * 16 + l15) * 16 + quad * 8]);
#pragma unroll
        for (int ni = 0; ni < 4; ++ni) {
            f32x4 s;
            for (int r = 0; r < 4; ++r) s[r] = 0.f;
            s = MFMA(ak, aq[ni], s);           // D[m=key][n=q]
            S4 u;
            u.b[0] = (__bf16)__expf(s[0]); u.b[1] = (__bf16)__expf(s[1]);
            u.b[2] = (__bf16)__expf(s[2]); u.b[3] = (__bf16)__expf(s[3]);
            *reinterpret_cast<short4*>(
                &p_lds[(oS * 64 + ni * 16 + l15) * 8 + sub]) = u.sh;
        }

        // barrier_B: P visible; DOES NOT drain vmcnt -> kt+1 DMA stays in flight
        asm volatile("s_waitcnt lgkmcnt(0)" ::: "memory");
        __builtin_amdgcn_s_barrier();
        asm volatile("" ::: "memory");
        __builtin_amdgcn_sched_barrier(0);

        // ---- PV phase: wave w owns ch-tiles {2w, 2w+1}
        const int chl = l15 & 7;
#pragma unroll
        for (int ks = 0; ks < 2; ++ks) {
            int pz = ((ks * 4 + quad) ^ chl);
            bf16x8 a0 = *reinterpret_cast<const bf16x8*>(
                &v_buf[cur][(((2 * w)     * 2 + (l15 >> 3)) * 64 + chl * 8 + pz) * 8]);
            bf16x8 a1 = *reinterpret_cast<const bf16x8*>(
                &v_buf[cur][(((2 * w + 1) * 2 + (l15 >> 3)) * 64 + chl * 8 + pz) * 8]);
            const int ob = (ks * 4 + quad) * 64;
            bf16x8 p0 = *reinterpret_cast<const bf16x8*>(&p_lds[(ob +  0 + l15) * 8]);
            bf16x8 p1 = *reinterpret_cast<const bf16x8*>(&p_lds[(ob + 16 + l15) * 8]);
            bf16x8 p2 = *reinterpret_cast<const bf16x8*>(&p_lds[(ob + 32 + l15) * 8]);
            bf16x8 p3 = *reinterpret_cast<const bf16x8*>(&p_lds[(ob + 48 + l15) * 8]);
            acc[0][0] = MFMA(a0, p0, acc[0][0]);
            acc[0][1] = MFMA(a0, p1, acc[0][1]);
            acc[0][2] = MFMA(a0, p2, acc[0][2]);
            acc[0][3] = MFMA(a0, p3, acc[0][3]);
            acc[1][0] = MFMA(a1, p0, acc[1][0]);
            acc[1][1] = MFMA(a1, p1, acc[1][1]);
            acc[1][2] = MFMA(a1, p2, acc[1][2]);
            acc[1][3] = MFMA(a1, p3, acc[1][3]);
            // l-sum: wave w reduces its own q-group (balanced across waves)
            bf16x8 pw = *reinterpret_cast<const bf16x8*>(&p_lds[(ob + w * 16 + l15) * 8]);
            lacc = MFMA(ones, pw, lacc);
        }
    }

    // write av partials: av_part[sp][n][c] fp32
    float* dst = av_part + (size_t)sp * 1024000;
    for (int mi = 0; mi < 2; ++mi)
        for (int ni = 0; ni < 4; ++ni) {
            int n  = n0q + ni * 16 + l15;
            int ch = (2 * w + mi) * 16 + quad * 4;
            *reinterpret_cast<f32x4*>(&dst[n * 128 + ch]) = acc[mi][ni];
        }
    if (quad == 0)
        l_part[sp * N_POS + n0q + w * 16 + l15] = lacc[0];
}

// ---------------------------------------------------------------------------
// Kernel C: split-K reduce + normalize (fp32) fused with y = wa @ av + ba
// (MFMA) + BN stats.  v4: n-tile 32->16, grid 250->500 (2 blocks/CU; was
// 1-block/CU latency-starved streaming 20.5 MB of av_part).
// ---------------------------------------------------------------------------
__global__ __launch_bounds__(256) void proj_out_kernel(
    const float* __restrict__ av_part, const float* __restrict__ l_part,
    const float* __restrict__ wa, const float* __restrict__ ba,
    float* __restrict__ y_ws, float* __restrict__ bn_sum, float* __restrict__ bn_sumsq)
{
    __shared__ __bf16 b_lds[2048];   // 16n x 128c fragment-packed, swizzled

    const int t    = threadIdx.x;
    const int n0   = blockIdx.x * 16;
    const int lane = t & 63;
    const int w    = t >> 6;
    const int l15  = lane & 15;
    const int quad = lane >> 4;

    // build normalized B tile: 256 c-octets, 1 per thread (coalesced reads)
    {
        int n = t >> 4, oc = t & 15;
        float l = 0.f;
#pragma unroll
        for (int s = 0; s < KSPLIT; ++s) l += l_part[s * N_POS + n0 + n];
        float4 a0 = make_float4(0.f, 0.f, 0.f, 0.f);
        float4 a1 = make_float4(0.f, 0.f, 0.f, 0.f);
#pragma unroll
        for (int s = 0; s < KSPLIT; ++s) {
            const float* p = av_part + (size_t)s * 1024000 + (n0 + n) * 128 + oc * 8;
            float4 u = *reinterpret_cast<const float4*>(p);
            float4 v = *reinterpret_cast<const float4*>(p + 4);
            a0.x += u.x; a0.y += u.y; a0.z += u.z; a0.w += u.w;
            a1.x += v.x; a1.y += v.y; a1.z += v.z; a1.w += v.w;
        }
        float inv = 1.f / l;
        union { int4 iv; __bf16 b[8]; } u;
        u.b[0]=(__bf16)(a0.x*inv); u.b[1]=(__bf16)(a0.y*inv);
        u.b[2]=(__bf16)(a0.z*inv); u.b[3]=(__bf16)(a0.w*inv);
        u.b[4]=(__bf16)(a1.x*inv); u.b[5]=(__bf16)(a1.y*inv);
        u.b[6]=(__bf16)(a1.z*inv); u.b[7]=(__bf16)(a1.w*inv);
        int slot = n ^ (oc & 7);
        *reinterpret_cast<int4*>(&b_lds[(oc * 16 + slot) * 8]) = u.iv;
    }

    // A-frags: wa rows for mtiles {2w, 2w+1}
    bf16x8 aw[2][4];
    f32x4  acc[2];
    for (int mi = 0; mi < 2; ++mi) {
        int mt = 2 * w + mi;
        const float* wrow = wa + (mt * 16 + l15) * 128;
        for (int ks = 0; ks < 4; ++ks) {
            float4 f0 = *reinterpret_cast<const float4*>(wrow + ks * 32 + quad * 8);
            float4 f1 = *reinterpret_cast<const float4*>(wrow + ks * 32 + quad * 8 + 4);
            bf16x8 a;
            a[0]=(__bf16)f0.x; a[1]=(__bf16)f0.y; a[2]=(__bf16)f0.z; a[3]=(__bf16)f0.w;
            a[4]=(__bf16)f1.x; a[5]=(__bf16)f1.y; a[6]=(__bf16)f1.z; a[7]=(__bf16)f1.w;
            aw[mi][ks] = a;
        }
        acc[mi][0] = ba[mt * 16 + quad * 4 + 0];
        acc[mi][1] = ba[mt * 16 + quad * 4 + 1];
        acc[mi][2] = ba[mt * 16 + quad * 4 + 2];
        acc[mi][3] = ba[mt * 16 + quad * 4 + 3];
    }
    __syncthreads();

    for (int ks = 0; ks < 4; ++ks) {
        int oc = ks * 4 + quad;
        int slot = l15 ^ (oc & 7);
        bf16x8 b0 = *reinterpret_cast<const bf16x8*>(&b_lds[(oc * 16 + slot) * 8]);
        for (int mi = 0; mi < 2; ++mi)
            acc[mi] = MFMA(aw[mi][ks], b0, acc[mi]);
    }

    // y writes [c][n] + BN partial stats
    for (int mi = 0; mi < 2; ++mi) {
        for (int r = 0; r < 4; ++r) {
            int ch = (2 * w + mi) * 16 + quad * 4 + r;
            float v0 = acc[mi][r];
            y_ws[ch * N_POS + n0 + l15] = v0;
            float s1 = v0;
            float s2 = v0 * v0;
#pragma unroll
            for (int off = 8; off >= 1; off >>= 1) {
                s1 += __shfl_xor(s1, off, 64);
                s2 += __shfl_xor(s2, off, 64);
            }
            if (l15 == 0) {
                atomicAdd(&bn_sum[ch],   s1);
                atomicAdd(&bn_sumsq[ch], s2);
            }
        }
    }
}

// ---------------------------------------------------------------------------
// Kernel D: BatchNorm (training stats) + ReLU + residual. grid 1000, block 256.
// ---------------------------------------------------------------------------
__global__ __launch_bounds__(256) void bn_relu_kernel(
    const float* __restrict__ y_ws, const float* __restrict__ x,
    const float* __restrict__ bn_sum, const float* __restrict__ bn_sumsq,
    const float* __restrict__ bn_w, const float* __restrict__ bn_b,
    float* __restrict__ out)
{
    const int i4 = blockIdx.x * 256 + threadIdx.x;
    const int c  = i4 / 2000;
    const float mean  = bn_sum[c]   * (1.f / 8000.f);
    const float var   = bn_sumsq[c] * (1.f / 8000.f) - mean * mean;
    const float rstd  = rsqrtf(var + 1e-5f);
    const float scale = bn_w[c] * rstd;
    const float shift = bn_b[c] - mean * scale;

    float4 y4 = reinterpret_cast<const float4*>(y_ws)[i4];
    float4 x4 = reinterpret_cast<const float4*>(x)[i4];
    float4 o4;
    o4.x = fmaxf(y4.x * scale + shift, 0.f) + x4.x;
    o4.y = fmaxf(y4.y * scale + shift, 0.f) + x4.y;
    o4.z = fmaxf(y4.z * scale + shift, 0.f) + x4.z;
    o4.w = fmaxf(y4.w * scale + shift, 0.f) + x4.w;
    reinterpret_cast<float4*>(out)[i4] = o4;
}

// ---------------------------------------------------------------------------
extern "C" void kernel_launch(void* const* d_in, const int* in_sizes, int n_in,
                              void* d_out, int out_size, void* d_ws, size_t ws_size,
                              hipStream_t stream)
{
    const float* x    = (const float*)d_in[0];
    const float* wq   = (const float*)d_in[1];
    const float* bq   = (const float*)d_in[2];
    const float* wk   = (const float*)d_in[3];
    const float* bk   = (const float*)d_in[4];
    const float* wv   = (const float*)d_in[5];
    const float* bv   = (const float*)d_in[6];
    const float* wa   = (const float*)d_in[7];
    const float* ba   = (const float*)d_in[8];
    const float* bn_w = (const float*)d_in[9];
    const float* bn_b = (const float*)d_in[10];
    float* out = (float*)d_out;

    char* base = (char*)d_ws;
    // byte layout (~27.3 MB):
    float*  av_part = (float*)base;                    // 20,480,000 B (5 x 8000 x 128 f32)
    __bf16* q_bf    = (__bf16*)(base + 20480000);      //    256,000 B
    __bf16* k_bf    = (__bf16*)(base + 20736000);      //    256,000 B
    __bf16* v_bf    = (__bf16*)(base + 20992000);      //  2,048,000 B
    float*  l_part  = (float*)(base + 23040000);       //    160,000 B
    float*  bn_sum   = (float*)(base + 23200000);      //        512 B
    float*  bn_sumsq = bn_sum + 128;                   //        512 B
    float*  y_ws    = (float*)(base + 23201024);       //  4,096,000 B

    hipMemsetAsync(bn_sum, 0, 1024, stream);
    qkv_kernel<<<500, 256, 0, stream>>>(x, wq, bq, wk, bk, wv, bv, q_bf, k_bf, v_bf);
    attn_kernel<<<QTILES * KSPLIT, 256, 0, stream>>>(q_bf, k_bf, v_bf, av_part, l_part);
    proj_out_kernel<<<500, 256, 0, stream>>>(av_part, l_part, wa, ba, y_ws, bn_sum, bn_sumsq);
    bn_relu_kernel<<<1000, 256, 0, stream>>>(y_ws, x, bn_sum, bn_sumsq, bn_w, bn_b, out);
}

// Round 4
// 168.265 us; speedup vs baseline: 1.2138x; 1.1256x over previous
//
#include <hip/hip_runtime.h>
#include <math.h>

#define N_POS 8000
#define C_CH  128
#define KSPLIT 5
#define KT_PER 25      // 125 k-tiles of 64 keys, 25 per split
#define QTILES 125     // q-tiles of 64 queries

typedef __bf16 bf16x8 __attribute__((ext_vector_type(8)));
typedef float  f32x4  __attribute__((ext_vector_type(4)));

#define MFMA(a,b,c) __builtin_amdgcn_mfma_f32_16x16x32_bf16((a),(b),(c),0,0,0)

// MFMA 16x16x32 lane layouts (verified m89/m120):
//   A[m][k]: m = lane&15, k = (lane>>4)*8 + j
//   B[k][n]: n = lane&15, k = (lane>>4)*8 + j
//   D[m][n]: n = lane&15, m = (lane>>4)*4 + reg

#define GLOAD_LDS(gp, lp) \
    __builtin_amdgcn_global_load_lds( \
        (const __attribute__((address_space(1))) void*)(gp), \
        (__attribute__((address_space(3))) void*)(lp), 16, 0, 0)

// ---------------------------------------------------------------------------
// Kernel A: QKV projections via MFMA. grid 250 (n-tiles of 32), block 256.
// (round-1 version; tile-16 variant regressed: halved staging ILP.)
// out rows: o 0..15 -> q, 16..31 -> k, 32..159 -> v(ch=o-32)
// q_bf,k_bf: [n][16] bf16.  v_bf: [c][8000] bf16.
// ---------------------------------------------------------------------------
__global__ __launch_bounds__(256) void qkv_kernel(
    const float* __restrict__ x,
    const float* __restrict__ wq, const float* __restrict__ bq,
    const float* __restrict__ wk, const float* __restrict__ bk,
    const float* __restrict__ wv, const float* __restrict__ bv,
    __bf16* __restrict__ q_bf, __bf16* __restrict__ k_bf, __bf16* __restrict__ v_bf)
{
    __shared__ __bf16 x_lds[32 * 136];          // [n][c]
    __shared__ __bf16 v_out[128 * 36];          // [ch][n]

    const int t    = threadIdx.x;
    const int n0   = blockIdx.x * 32;
    const int lane = t & 63;
    const int w    = t >> 6;
    const int l15  = lane & 15;
    const int quad = lane >> 4;

    // stage x tile [128c x 32n] -> x_lds[n][c] bf16 (transpose+convert)
    for (int r = 0; r < 4; ++r) {
        int f = r * 256 + t;
        int ch = f >> 3, n4 = f & 7;
        float4 xv = *reinterpret_cast<const float4*>(&x[ch * N_POS + n0 + n4 * 4]);
        x_lds[(n4 * 4 + 0) * 136 + ch] = (__bf16)xv.x;
        x_lds[(n4 * 4 + 1) * 136 + ch] = (__bf16)xv.y;
        x_lds[(n4 * 4 + 2) * 136 + ch] = (__bf16)xv.z;
        x_lds[(n4 * 4 + 3) * 136 + ch] = (__bf16)xv.w;
    }

    // A-frags: weight rows fp32->bf16 in regs. wave w owns mtiles {w, w+4, w+8<10}
    bf16x8 aw[3][4];
    f32x4  acc[3][2];
    const int nmt = (w < 2) ? 3 : 2;
    for (int mi = 0; mi < nmt; ++mi) {
        int mt = w + 4 * mi;
        const float *wrow, *brow;
        if (mt == 0)      { wrow = wq + l15 * 128;               brow = bq; }
        else if (mt == 1) { wrow = wk + l15 * 128;               brow = bk; }
        else              { wrow = wv + ((mt - 2) * 16 + l15) * 128;
                            brow = bv + (mt - 2) * 16; }
        for (int ks = 0; ks < 4; ++ks) {
            float4 f0 = *reinterpret_cast<const float4*>(wrow + ks * 32 + quad * 8);
            float4 f1 = *reinterpret_cast<const float4*>(wrow + ks * 32 + quad * 8 + 4);
            bf16x8 a;
            a[0]=(__bf16)f0.x; a[1]=(__bf16)f0.y; a[2]=(__bf16)f0.z; a[3]=(__bf16)f0.w;
            a[4]=(__bf16)f1.x; a[5]=(__bf16)f1.y; a[6]=(__bf16)f1.z; a[7]=(__bf16)f1.w;
            aw[mi][ks] = a;
        }
        for (int ni = 0; ni < 2; ++ni) {
            acc[mi][ni][0] = brow[quad * 4 + 0]; acc[mi][ni][1] = brow[quad * 4 + 1];
            acc[mi][ni][2] = brow[quad * 4 + 2]; acc[mi][ni][3] = brow[quad * 4 + 3];
        }
    }
    __syncthreads();

    for (int ks = 0; ks < 4; ++ks) {
        bf16x8 b0 = *reinterpret_cast<const bf16x8*>(&x_lds[(0  + l15) * 136 + ks * 32 + quad * 8]);
        bf16x8 b1 = *reinterpret_cast<const bf16x8*>(&x_lds[(16 + l15) * 136 + ks * 32 + quad * 8]);
        for (int mi = 0; mi < nmt; ++mi) {
            acc[mi][0] = MFMA(aw[mi][ks], b0, acc[mi][0]);
            acc[mi][1] = MFMA(aw[mi][ks], b1, acc[mi][1]);
        }
    }

    union S4 { short4 s; __bf16 b[4]; };
    for (int mi = 0; mi < nmt; ++mi) {
        int mt = w + 4 * mi;
        for (int ni = 0; ni < 2; ++ni) {
            S4 u;
            u.b[0]=(__bf16)acc[mi][ni][0]; u.b[1]=(__bf16)acc[mi][ni][1];
            u.b[2]=(__bf16)acc[mi][ni][2]; u.b[3]=(__bf16)acc[mi][ni][3];
            int n = n0 + ni * 16 + l15;
            if (mt == 0) {
                *reinterpret_cast<short4*>(&q_bf[n * 16 + quad * 4]) = u.s;
            } else if (mt == 1) {
                *reinterpret_cast<short4*>(&k_bf[n * 16 + quad * 4]) = u.s;
            } else {
                int ch0 = (mt - 2) * 16 + quad * 4;
                int nl  = ni * 16 + l15;
                v_out[(ch0 + 0) * 36 + nl] = u.b[0];
                v_out[(ch0 + 1) * 36 + nl] = u.b[1];
                v_out[(ch0 + 2) * 36 + nl] = u.b[2];
                v_out[(ch0 + 3) * 36 + nl] = u.b[3];
            }
        }
    }
    __syncthreads();
    for (int r = 0; r < 4; ++r) {
        int f = r * 256 + t;
        int ch = f >> 3, n4 = f & 7;
        int2 d = *reinterpret_cast<const int2*>(&v_out[ch * 36 + n4 * 4]);
        *reinterpret_cast<int2*>(&v_bf[ch * N_POS + n0 + n4 * 4]) = d;
    }
}

// ---------------------------------------------------------------------------
// Kernel B: fused attention, split-K, MFMA, global_load_lds double-buffer.
// (round-1 version, verified ~39 us.)
// ---------------------------------------------------------------------------
__global__ __launch_bounds__(256, 3) void attn_kernel(
    const __bf16* __restrict__ q_bf, const __bf16* __restrict__ k_bf,
    const __bf16* __restrict__ v_bf, float* __restrict__ av_part,
    float* __restrict__ l_part)
{
    __shared__ __bf16 v_buf[2][8192];   // 16 KB each
    __shared__ __bf16 k_buf[2][1024];   // 2 KB each
    __shared__ __bf16 p_lds[4096];      // 8 KB; total 45056 B -> 3 blocks/CU

    const int t    = threadIdx.x;
    const int qt   = blockIdx.x % QTILES;
    const int sp   = blockIdx.x / QTILES;
    const int n0q  = qt * 64;
    const int lane = t & 63;
    const int w    = t >> 6;
    const int l15  = lane & 15;
    const int quad = lane >> 4;

    // staging maps (per lane, loop-invariant)
    const int chL   = lane >> 3;              // V: low 3 bits of channel
    const int vpart = (lane & 7) ^ chL;       // V: key-octet (XOR swizzle)
    const int kkey  = lane >> 1;              // K: key within 32-key half
    const int khalf = lane & 1;               // K: dim half

    // Q B-frags in registers (k-dim 16 padded to 32 with zeros), 4 q-groups
    bf16x8 aq[4];
    for (int ni = 0; ni < 4; ++ni) {
        for (int j = 0; j < 8; ++j) aq[ni][j] = (__bf16)0.0f;
        if (quad < 2)
            aq[ni] = *reinterpret_cast<const bf16x8*>(
                &q_bf[(n0q + ni * 16 + l15) * 16 + quad * 8]);
    }
    bf16x8 ones;
    for (int j = 0; j < 8; ++j) ones[j] = (__bf16)1.0f;

    f32x4 acc[2][4];
    for (int mi = 0; mi < 2; ++mi)
        for (int ni = 0; ni < 4; ++ni)
            for (int r = 0; r < 4; ++r) acc[mi][ni][r] = 0.f;
    f32x4 lacc;
    for (int r = 0; r < 4; ++r) lacc[r] = 0.f;

    const int kt0 = sp * KT_PER;

    // issue one tile's staging DMA: 4 V ops per wave; K ops on waves 0,1 only
    auto stage = [&](int kt, int buf) {
        const int n0k = kt * 64;
        for (int r = 0; r < 4; ++r) {
            int R = w * 4 + r;   // wave-uniform LDS base
            GLOAD_LDS(v_bf + (8 * R + chL) * N_POS + n0k + vpart * 8,
                      &v_buf[buf][R * 512]);
        }
        if (w < 2)
            GLOAD_LDS(k_bf + (size_t)(n0k + w * 32 + kkey) * 16 + khalf * 8,
                      &k_buf[buf][w * 512]);
    };

    stage(kt0, 0);

    const int oS  = w * 2 + (quad >> 1);   // P-write octet
    const int sub = (quad & 1) * 4;        // P-write elem offset in chunk

    union S4 { short4 sh; __bf16 b[4]; };

    for (int kt = kt0; kt < kt0 + KT_PER; ++kt) {
        const int cur = (kt - kt0) & 1;
        __syncthreads();   // barrier_A: vmcnt(0) drain of tile-kt DMA (1 iter of cover)

        // issue next tile's DMA NOW -> in flight across S + barrier_B + PV
        if (kt + 1 < kt0 + KT_PER) stage(kt + 1, cur ^ 1);

        // ---- S phase: A = K rows (wave w -> keys w*16..+15), B = Q regs
        bf16x8 ak;
        for (int j = 0; j < 8; ++j) ak[j] = (__bf16)0.0f;
        if (quad < 2)
            ak = *reinterpret_cast<const bf16x8*>(
                &k_buf[cur][(w * 16 + l15) * 16 + quad * 8]);
#pragma unroll
        for (int ni = 0; ni < 4; ++ni) {
            f32x4 s;
            for (int r = 0; r < 4; ++r) s[r] = 0.f;
            s = MFMA(ak, aq[ni], s);           // D[m=key][n=q]
            S4 u;
            u.b[0] = (__bf16)__expf(s[0]); u.b[1] = (__bf16)__expf(s[1]);
            u.b[2] = (__bf16)__expf(s[2]); u.b[3] = (__bf16)__expf(s[3]);
            *reinterpret_cast<short4*>(
                &p_lds[(oS * 64 + ni * 16 + l15) * 8 + sub]) = u.sh;
        }

        // barrier_B: P visible; DOES NOT drain vmcnt -> kt+1 DMA stays in flight
        asm volatile("s_waitcnt lgkmcnt(0)" ::: "memory");
        __builtin_amdgcn_s_barrier();
        asm volatile("" ::: "memory");
        __builtin_amdgcn_sched_barrier(0);

        // ---- PV phase: wave w owns ch-tiles {2w, 2w+1}
        const int chl = l15 & 7;
#pragma unroll
        for (int ks = 0; ks < 2; ++ks) {
            int pz = ((ks * 4 + quad) ^ chl);
            bf16x8 a0 = *reinterpret_cast<const bf16x8*>(
                &v_buf[cur][(((2 * w)     * 2 + (l15 >> 3)) * 64 + chl * 8 + pz) * 8]);
            bf16x8 a1 = *reinterpret_cast<const bf16x8*>(
                &v_buf[cur][(((2 * w + 1) * 2 + (l15 >> 3)) * 64 + chl * 8 + pz) * 8]);
            const int ob = (ks * 4 + quad) * 64;
            bf16x8 p0 = *reinterpret_cast<const bf16x8*>(&p_lds[(ob +  0 + l15) * 8]);
            bf16x8 p1 = *reinterpret_cast<const bf16x8*>(&p_lds[(ob + 16 + l15) * 8]);
            bf16x8 p2 = *reinterpret_cast<const bf16x8*>(&p_lds[(ob + 32 + l15) * 8]);
            bf16x8 p3 = *reinterpret_cast<const bf16x8*>(&p_lds[(ob + 48 + l15) * 8]);
            acc[0][0] = MFMA(a0, p0, acc[0][0]);
            acc[0][1] = MFMA(a0, p1, acc[0][1]);
            acc[0][2] = MFMA(a0, p2, acc[0][2]);
            acc[0][3] = MFMA(a0, p3, acc[0][3]);
            acc[1][0] = MFMA(a1, p0, acc[1][0]);
            acc[1][1] = MFMA(a1, p1, acc[1][1]);
            acc[1][2] = MFMA(a1, p2, acc[1][2]);
            acc[1][3] = MFMA(a1, p3, acc[1][3]);
            // l-sum: wave w reduces its own q-group (balanced across waves)
            bf16x8 pw = *reinterpret_cast<const bf16x8*>(&p_lds[(ob + w * 16 + l15) * 8]);
            lacc = MFMA(ones, pw, lacc);
        }
    }

    // write av partials: av_part[sp][n][c] fp32
    float* dst = av_part + (size_t)sp * 1024000;
    for (int mi = 0; mi < 2; ++mi)
        for (int ni = 0; ni < 4; ++ni) {
            int n  = n0q + ni * 16 + l15;
            int ch = (2 * w + mi) * 16 + quad * 4;
            *reinterpret_cast<f32x4*>(&dst[n * 128 + ch]) = acc[mi][ni];
        }
    if (quad == 0)
        l_part[sp * N_POS + n0q + w * 16 + l15] = lacc[0];
}

// ---------------------------------------------------------------------------
// Kernel C1: split-K reduce + 1/l normalize + bf16 pack.  Pure streaming,
// grid 500 x 256: thread i owns 8 consecutive floats of av[n][c]; 10
// independent b128 reads in flight + coalesced 16B write.  This removes the
// latency-chain reduce from the GEMM kernel (round-3 proj_out: VALUBusy 1.9%,
// 57 us -- pure latency on scattered av_part reads).
// ---------------------------------------------------------------------------
__global__ __launch_bounds__(256) void reduce_kernel(
    const float* __restrict__ av_part, const float* __restrict__ l_part,
    __bf16* __restrict__ av_bf)
{
    const int i = blockIdx.x * 256 + threadIdx.x;    // 0..127999
    const int n = i >> 4;                            // row (16 threads/row)

    float l = 0.f;
#pragma unroll
    for (int s = 0; s < KSPLIT; ++s) l += l_part[s * N_POS + n];

    float4 a0 = make_float4(0.f, 0.f, 0.f, 0.f);
    float4 a1 = make_float4(0.f, 0.f, 0.f, 0.f);
#pragma unroll
    for (int s = 0; s < KSPLIT; ++s) {
        const float* p = av_part + (size_t)s * 1024000 + i * 8;
        float4 u = *reinterpret_cast<const float4*>(p);
        float4 v = *reinterpret_cast<const float4*>(p + 4);
        a0.x += u.x; a0.y += u.y; a0.z += u.z; a0.w += u.w;
        a1.x += v.x; a1.y += v.y; a1.z += v.z; a1.w += v.w;
    }
    float inv = 1.f / l;
    union { int4 iv; __bf16 b[8]; } u;
    u.b[0]=(__bf16)(a0.x*inv); u.b[1]=(__bf16)(a0.y*inv);
    u.b[2]=(__bf16)(a0.z*inv); u.b[3]=(__bf16)(a0.w*inv);
    u.b[4]=(__bf16)(a1.x*inv); u.b[5]=(__bf16)(a1.y*inv);
    u.b[6]=(__bf16)(a1.z*inv); u.b[7]=(__bf16)(a1.w*inv);
    *reinterpret_cast<int4*>(&av_bf[i * 8]) = u.iv;
}

// ---------------------------------------------------------------------------
// Kernel C2: y = wa @ av + ba (MFMA) + BN stats.  grid 250 (n-tile 32).
// Round-1 structure; the b_lds build now reads pre-normalized bf16 av
// directly (one int4 = one fragment octet), no split reduce in this kernel.
// ---------------------------------------------------------------------------
__global__ __launch_bounds__(256) void proj_out_kernel(
    const __bf16* __restrict__ av_bf,
    const float* __restrict__ wa, const float* __restrict__ ba,
    float* __restrict__ y_ws, float* __restrict__ bn_sum, float* __restrict__ bn_sumsq)
{
    __shared__ __bf16 b_lds[4096];   // 32n x 128c fragment-packed, swizzled

    const int t    = threadIdx.x;
    const int n0   = blockIdx.x * 32;
    const int lane = t & 63;
    const int w    = t >> 6;
    const int l15  = lane & 15;
    const int quad = lane >> 4;

    // build B tile: 512 c-octets, 2 per thread (coalesced 16B reads, L2-hot)
    for (int r = 0; r < 2; ++r) {
        int g = r * 256 + t;
        int n = g >> 4, oc = g & 15;
        int4 u = *reinterpret_cast<const int4*>(&av_bf[(n0 + n) * 128 + oc * 8]);
        int A = (n >> 4) * 16 + oc;
        int slot = (n & 15) ^ (oc & 7);
        *reinterpret_cast<int4*>(&b_lds[(A * 16 + slot) * 8]) = u;
    }

    // A-frags: wa rows for mtiles {2w, 2w+1}
    bf16x8 aw[2][4];
    f32x4  acc[2][2];
    for (int mi = 0; mi < 2; ++mi) {
        int mt = 2 * w + mi;
        const float* wrow = wa + (mt * 16 + l15) * 128;
        for (int ks = 0; ks < 4; ++ks) {
            float4 f0 = *reinterpret_cast<const float4*>(wrow + ks * 32 + quad * 8);
            float4 f1 = *reinterpret_cast<const float4*>(wrow + ks * 32 + quad * 8 + 4);
            bf16x8 a;
            a[0]=(__bf16)f0.x; a[1]=(__bf16)f0.y; a[2]=(__bf16)f0.z; a[3]=(__bf16)f0.w;
            a[4]=(__bf16)f1.x; a[5]=(__bf16)f1.y; a[6]=(__bf16)f1.z; a[7]=(__bf16)f1.w;
            aw[mi][ks] = a;
        }
        for (int ni = 0; ni < 2; ++ni) {
            acc[mi][ni][0] = ba[mt * 16 + quad * 4 + 0];
            acc[mi][ni][1] = ba[mt * 16 + quad * 4 + 1];
            acc[mi][ni][2] = ba[mt * 16 + quad * 4 + 2];
            acc[mi][ni][3] = ba[mt * 16 + quad * 4 + 3];
        }
    }
    __syncthreads();

    for (int ks = 0; ks < 4; ++ks) {
        int oc = ks * 4 + quad;
        int slot = l15 ^ (oc & 7);
        bf16x8 b0 = *reinterpret_cast<const bf16x8*>(&b_lds[((0  + oc) * 16 + slot) * 8]);
        bf16x8 b1 = *reinterpret_cast<const bf16x8*>(&b_lds[((16 + oc) * 16 + slot) * 8]);
        for (int mi = 0; mi < 2; ++mi) {
            acc[mi][0] = MFMA(aw[mi][ks], b0, acc[mi][0]);
            acc[mi][1] = MFMA(aw[mi][ks], b1, acc[mi][1]);
        }
    }

    // y writes [c][n] + BN partial stats
    for (int mi = 0; mi < 2; ++mi) {
        for (int r = 0; r < 4; ++r) {
            int ch = (2 * w + mi) * 16 + quad * 4 + r;
            float v0 = acc[mi][0][r];
            float v1 = acc[mi][1][r];
            y_ws[ch * N_POS + n0 + 0  + l15] = v0;
            y_ws[ch * N_POS + n0 + 16 + l15] = v1;
            float s1 = v0 + v1;
            float s2 = v0 * v0 + v1 * v1;
#pragma unroll
            for (int off = 8; off >= 1; off >>= 1) {
                s1 += __shfl_xor(s1, off, 64);
                s2 += __shfl_xor(s2, off, 64);
            }
            if (l15 == 0) {
                atomicAdd(&bn_sum[ch],   s1);
                atomicAdd(&bn_sumsq[ch], s2);
            }
        }
    }
}

// ---------------------------------------------------------------------------
// Kernel D: BatchNorm (training stats) + ReLU + residual. grid 1000, block 256.
// ---------------------------------------------------------------------------
__global__ __launch_bounds__(256) void bn_relu_kernel(
    const float* __restrict__ y_ws, const float* __restrict__ x,
    const float* __restrict__ bn_sum, const float* __restrict__ bn_sumsq,
    const float* __restrict__ bn_w, const float* __restrict__ bn_b,
    float* __restrict__ out)
{
    const int i4 = blockIdx.x * 256 + threadIdx.x;
    const int c  = i4 / 2000;
    const float mean  = bn_sum[c]   * (1.f / 8000.f);
    const float var   = bn_sumsq[c] * (1.f / 8000.f) - mean * mean;
    const float rstd  = rsqrtf(var + 1e-5f);
    const float scale = bn_w[c] * rstd;
    const float shift = bn_b[c] - mean * scale;

    float4 y4 = reinterpret_cast<const float4*>(y_ws)[i4];
    float4 x4 = reinterpret_cast<const float4*>(x)[i4];
    float4 o4;
    o4.x = fmaxf(y4.x * scale + shift, 0.f) + x4.x;
    o4.y = fmaxf(y4.y * scale + shift, 0.f) + x4.y;
    o4.z = fmaxf(y4.z * scale + shift, 0.f) + x4.z;
    o4.w = fmaxf(y4.w * scale + shift, 0.f) + x4.w;
    reinterpret_cast<float4*>(out)[i4] = o4;
}

// ---------------------------------------------------------------------------
extern "C" void kernel_launch(void* const* d_in, const int* in_sizes, int n_in,
                              void* d_out, int out_size, void* d_ws, size_t ws_size,
                              hipStream_t stream)
{
    const float* x    = (const float*)d_in[0];
    const float* wq   = (const float*)d_in[1];
    const float* bq   = (const float*)d_in[2];
    const float* wk   = (const float*)d_in[3];
    const float* bk   = (const float*)d_in[4];
    const float* wv   = (const float*)d_in[5];
    const float* bv   = (const float*)d_in[6];
    const float* wa   = (const float*)d_in[7];
    const float* ba   = (const float*)d_in[8];
    const float* bn_w = (const float*)d_in[9];
    const float* bn_b = (const float*)d_in[10];
    float* out = (float*)d_out;

    char* base = (char*)d_ws;
    // byte layout (~29.3 MB):
    float*  av_part = (float*)base;                    // 20,480,000 B (5 x 8000 x 128 f32)
    __bf16* q_bf    = (__bf16*)(base + 20480000);      //    256,000 B
    __bf16* k_bf    = (__bf16*)(base + 20736000);      //    256,000 B
    __bf16* v_bf    = (__bf16*)(base + 20992000);      //  2,048,000 B
    float*  l_part  = (float*)(base + 23040000);       //    160,000 B
    float*  bn_sum   = (float*)(base + 23200000);      //        512 B
    float*  bn_sumsq = bn_sum + 128;                   //        512 B
    float*  y_ws    = (float*)(base + 23201024);       //  4,096,000 B
    __bf16* av_bf   = (__bf16*)(base + 27297024);      //  2,048,000 B

    hipMemsetAsync(bn_sum, 0, 1024, stream);
    qkv_kernel<<<250, 256, 0, stream>>>(x, wq, bq, wk, bk, wv, bv, q_bf, k_bf, v_bf);
    attn_kernel<<<QTILES * KSPLIT, 256, 0, stream>>>(q_bf, k_bf, v_bf, av_part, l_part);
    reduce_kernel<<<500, 256, 0, stream>>>(av_part, l_part, av_bf);
    proj_out_kernel<<<250, 256, 0, stream>>>(av_bf, wa, ba, y_ws, bn_sum, bn_sumsq);
    bn_relu_kernel<<<1000, 256, 0, stream>>>(y_ws, x, bn_sum, bn_sumsq, bn_w, bn_b, out);
}

// Round 5
// 163.282 us; speedup vs baseline: 1.2509x; 1.0305x over previous
//
#include <hip/hip_runtime.h>
#include <math.h>

#define N_POS 8000
#define C_CH  128
#define KSPLIT 5
#define KT_PER 25      // 125 k-tiles of 64 keys, 25 per split
#define QTILES 125     // q-tiles of 64 queries

typedef __bf16 bf16x8 __attribute__((ext_vector_type(8)));
typedef float  f32x4  __attribute__((ext_vector_type(4)));

#define MFMA(a,b,c) __builtin_amdgcn_mfma_f32_16x16x32_bf16((a),(b),(c),0,0,0)

// MFMA 16x16x32 lane layouts (verified m89/m120):
//   A[m][k]: m = lane&15, k = (lane>>4)*8 + j
//   B[k][n]: n = lane&15, k = (lane>>4)*8 + j
//   D[m][n]: n = lane&15, m = (lane>>4)*4 + reg

#define GLOAD_LDS(gp, lp) \
    __builtin_amdgcn_global_load_lds( \
        (const __attribute__((address_space(1))) void*)(gp), \
        (__attribute__((address_space(3))) void*)(lp), 16, 0, 0)

// ---------------------------------------------------------------------------
// Kernel A: QKV projections via MFMA. grid 250 (n-tiles of 32), block 256.
// (round-1 version, best measured.)
// out rows: o 0..15 -> q, 16..31 -> k, 32..159 -> v(ch=o-32)
// q_bf,k_bf: [n][16] bf16.  v_bf: [c][8000] bf16.
// ---------------------------------------------------------------------------
__global__ __launch_bounds__(256) void qkv_kernel(
    const float* __restrict__ x,
    const float* __restrict__ wq, const float* __restrict__ bq,
    const float* __restrict__ wk, const float* __restrict__ bk,
    const float* __restrict__ wv, const float* __restrict__ bv,
    __bf16* __restrict__ q_bf, __bf16* __restrict__ k_bf, __bf16* __restrict__ v_bf)
{
    __shared__ __bf16 x_lds[32 * 136];          // [n][c]
    __shared__ __bf16 v_out[128 * 36];          // [ch][n]

    const int t    = threadIdx.x;
    const int n0   = blockIdx.x * 32;
    const int lane = t & 63;
    const int w    = t >> 6;
    const int l15  = lane & 15;
    const int quad = lane >> 4;

    // stage x tile [128c x 32n] -> x_lds[n][c] bf16 (transpose+convert)
    for (int r = 0; r < 4; ++r) {
        int f = r * 256 + t;
        int ch = f >> 3, n4 = f & 7;
        float4 xv = *reinterpret_cast<const float4*>(&x[ch * N_POS + n0 + n4 * 4]);
        x_lds[(n4 * 4 + 0) * 136 + ch] = (__bf16)xv.x;
        x_lds[(n4 * 4 + 1) * 136 + ch] = (__bf16)xv.y;
        x_lds[(n4 * 4 + 2) * 136 + ch] = (__bf16)xv.z;
        x_lds[(n4 * 4 + 3) * 136 + ch] = (__bf16)xv.w;
    }

    // A-frags: weight rows fp32->bf16 in regs. wave w owns mtiles {w, w+4, w+8<10}
    bf16x8 aw[3][4];
    f32x4  acc[3][2];
    const int nmt = (w < 2) ? 3 : 2;
    for (int mi = 0; mi < nmt; ++mi) {
        int mt = w + 4 * mi;
        const float *wrow, *brow;
        if (mt == 0)      { wrow = wq + l15 * 128;               brow = bq; }
        else if (mt == 1) { wrow = wk + l15 * 128;               brow = bk; }
        else              { wrow = wv + ((mt - 2) * 16 + l15) * 128;
                            brow = bv + (mt - 2) * 16; }
        for (int ks = 0; ks < 4; ++ks) {
            float4 f0 = *reinterpret_cast<const float4*>(wrow + ks * 32 + quad * 8);
            float4 f1 = *reinterpret_cast<const float4*>(wrow + ks * 32 + quad * 8 + 4);
            bf16x8 a;
            a[0]=(__bf16)f0.x; a[1]=(__bf16)f0.y; a[2]=(__bf16)f0.z; a[3]=(__bf16)f0.w;
            a[4]=(__bf16)f1.x; a[5]=(__bf16)f1.y; a[6]=(__bf16)f1.z; a[7]=(__bf16)f1.w;
            aw[mi][ks] = a;
        }
        for (int ni = 0; ni < 2; ++ni) {
            acc[mi][ni][0] = brow[quad * 4 + 0]; acc[mi][ni][1] = brow[quad * 4 + 1];
            acc[mi][ni][2] = brow[quad * 4 + 2]; acc[mi][ni][3] = brow[quad * 4 + 3];
        }
    }
    __syncthreads();

    for (int ks = 0; ks < 4; ++ks) {
        bf16x8 b0 = *reinterpret_cast<const bf16x8*>(&x_lds[(0  + l15) * 136 + ks * 32 + quad * 8]);
        bf16x8 b1 = *reinterpret_cast<const bf16x8*>(&x_lds[(16 + l15) * 136 + ks * 32 + quad * 8]);
        for (int mi = 0; mi < nmt; ++mi) {
            acc[mi][0] = MFMA(aw[mi][ks], b0, acc[mi][0]);
            acc[mi][1] = MFMA(aw[mi][ks], b1, acc[mi][1]);
        }
    }

    union S4 { short4 s; __bf16 b[4]; };
    for (int mi = 0; mi < nmt; ++mi) {
        int mt = w + 4 * mi;
        for (int ni = 0; ni < 2; ++ni) {
            S4 u;
            u.b[0]=(__bf16)acc[mi][ni][0]; u.b[1]=(__bf16)acc[mi][ni][1];
            u.b[2]=(__bf16)acc[mi][ni][2]; u.b[3]=(__bf16)acc[mi][ni][3];
            int n = n0 + ni * 16 + l15;
            if (mt == 0) {
                *reinterpret_cast<short4*>(&q_bf[n * 16 + quad * 4]) = u.s;
            } else if (mt == 1) {
                *reinterpret_cast<short4*>(&k_bf[n * 16 + quad * 4]) = u.s;
            } else {
                int ch0 = (mt - 2) * 16 + quad * 4;
                int nl  = ni * 16 + l15;
                v_out[(ch0 + 0) * 36 + nl] = u.b[0];
                v_out[(ch0 + 1) * 36 + nl] = u.b[1];
                v_out[(ch0 + 2) * 36 + nl] = u.b[2];
                v_out[(ch0 + 3) * 36 + nl] = u.b[3];
            }
        }
    }
    __syncthreads();
    for (int r = 0; r < 4; ++r) {
        int f = r * 256 + t;
        int ch = f >> 3, n4 = f & 7;
        int2 d = *reinterpret_cast<const int2*>(&v_out[ch * 36 + n4 * 4]);
        *reinterpret_cast<int2*>(&v_bf[ch * N_POS + n0 + n4 * 4]) = d;
    }
}

// ---------------------------------------------------------------------------
// Kernel B v5: fused attention, split-K.  ONE barrier per k-tile.
//
// Data-coupling analysis: V is wave-SELF-staged (wave w DMAs ch 32w..32w+31
// and PV-reads exactly those rows); K's A-fragment is 16B/lane contiguous in
// k_bf -> lives in registers (kA/kB double-buffer, upper k-half zero).  Only
// P crosses waves -> double-buffered p_lds protected by the single s_barrier.
// V/K completion is a counted s_waitcnt vmcnt(5): the 5 prefetch loads for
// kt+1 (4 gload_lds V + 1 global K) stay in flight across S+barrier+PV --
// never drained to 0 in the main loop (T3/T4 pattern).
//
// Per iter kt:
//   stage V(kt+1) DMA -> v_buf[(kt+1)&1]; load K(kt+1) -> kn regs
//   s_waitcnt vmcnt(5): V(kt)/K(kt) complete, prefetch still in flight
//   S: 4 MFMA (kc x Q regs) -> exp -> bf16 -> p_lds[pbuf]; lp += quantized sums
//   s_waitcnt lgkmcnt(0); s_barrier          (P visible; nothing drained)
//   PV: 16 MFMA from v_buf[kt&1] (XOR-swizzled, conflict-free) x p_lds[pbuf]
//
// LDS: v_buf 2x16KB + p_lds 2x8KB = 48KB -> 3 blocks/CU.
// ---------------------------------------------------------------------------
__global__ __launch_bounds__(256, 3) void attn_kernel(
    const __bf16* __restrict__ q_bf, const __bf16* __restrict__ k_bf,
    const __bf16* __restrict__ v_bf, float* __restrict__ av_part,
    float* __restrict__ l_part)
{
    __shared__ __bf16 v_buf[2][8192];   // 16 KB each
    __shared__ __bf16 p_lds[2][4096];   // 8 KB each

    const int t    = threadIdx.x;
    const int qt   = blockIdx.x % QTILES;
    const int sp   = blockIdx.x / QTILES;
    const int n0q  = qt * 64;
    const int lane = t & 63;
    const int w    = t >> 6;
    const int l15  = lane & 15;
    const int quad = lane >> 4;

    // V staging map (per lane, loop-invariant)
    const int chL   = lane >> 3;              // low 3 bits of channel
    const int vpart = (lane & 7) ^ chL;       // key-octet (XOR swizzle)

    // Q B-frags in registers (k-dim 16 padded to 32 with zeros), 4 q-groups
    bf16x8 aq[4];
    for (int ni = 0; ni < 4; ++ni) {
        for (int j = 0; j < 8; ++j) aq[ni][j] = (__bf16)0.0f;
        if (quad < 2)
            aq[ni] = *reinterpret_cast<const bf16x8*>(
                &q_bf[(n0q + ni * 16 + l15) * 16 + quad * 8]);
    }

    f32x4 acc[2][4];
    for (int mi = 0; mi < 2; ++mi)
        for (int ni = 0; ni < 4; ++ni)
            for (int r = 0; r < 4; ++r) acc[mi][ni][r] = 0.f;
    float lp[4] = {0.f, 0.f, 0.f, 0.f};

    const int kt0   = sp * KT_PER;
    const int ktEnd = kt0 + KT_PER;

    // stage one tile's V: 4 gload_lds per wave, self-consumed rows
    auto stageV = [&](int kt) {
        const int n0k = kt * 64;
        __bf16* vb = &v_buf[kt & 1][0];
        for (int r = 0; r < 4; ++r) {
            int R = w * 4 + r;   // wave-uniform LDS base; ch 8R..8R+7
            GLOAD_LDS(v_bf + (8 * R + chL) * N_POS + n0k + vpart * 8,
                      &vb[R * 512]);
        }
    };

    // K double-buffer in regs (zero-init once; lanes 32-63 stay zero forever)
    bf16x8 kA, kB;
    for (int j = 0; j < 8; ++j) { kA[j] = (__bf16)0.0f; kB[j] = (__bf16)0.0f; }

    stageV(kt0);
    if (quad < 2)
        kA = *reinterpret_cast<const bf16x8*>(
            &k_bf[(size_t)(kt0 * 64 + w * 16 + l15) * 16 + quad * 8]);

    const int oS  = w * 2 + (quad >> 1);   // P-write octet
    const int sub = (quad & 1) * 4;        // P-write elem offset in chunk

    union S4 { short4 sh; __bf16 b[4]; };

    auto iter = [&](int kt, bf16x8& kc, bf16x8& kn, int pbuf) {
        const bool last = (kt + 1 >= ktEnd);
        if (!last) {
            stageV(kt + 1);
            if (quad < 2)
                kn = *reinterpret_cast<const bf16x8*>(
                    &k_bf[(size_t)((kt + 1) * 64 + w * 16 + l15) * 16 + quad * 8]);
            asm volatile("s_waitcnt vmcnt(5)" ::: "memory");
        } else {
            asm volatile("s_waitcnt vmcnt(0)" ::: "memory");
        }
        __builtin_amdgcn_sched_barrier(0);

        // ---- S phase: A = K regs (wave w -> keys w*16..+15), B = Q regs
        __bf16* pb = &p_lds[pbuf][0];
#pragma unroll
        for (int ni = 0; ni < 4; ++ni) {
            f32x4 s;
            for (int r = 0; r < 4; ++r) s[r] = 0.f;
            s = MFMA(kc, aq[ni], s);           // D[m=key][n=q]
            S4 u;
            u.b[0] = (__bf16)__expf(s[0]); u.b[1] = (__bf16)__expf(s[1]);
            u.b[2] = (__bf16)__expf(s[2]); u.b[3] = (__bf16)__expf(s[3]);
            *reinterpret_cast<short4*>(
                &pb[(oS * 64 + ni * 16 + l15) * 8 + sub]) = u.sh;
            // l partial: per-lane sum of QUANTIZED p (this lane's 4 keys);
            // quad-reduce deferred to epilogue
            lp[ni] += (float)u.b[0] + (float)u.b[1]
                    + (float)u.b[2] + (float)u.b[3];
        }

        // single barrier: P[pbuf] visible; prefetch stays in flight
        asm volatile("s_waitcnt lgkmcnt(0)" ::: "memory");
        __builtin_amdgcn_s_barrier();
        __builtin_amdgcn_sched_barrier(0);

        // ---- PV phase: wave w owns ch-tiles {2w, 2w+1} (self-staged V)
        const __bf16* vb = &v_buf[kt & 1][0];
        const __bf16* pr = &p_lds[pbuf][0];
        const int chl = l15 & 7;
#pragma unroll
        for (int ks = 0; ks < 2; ++ks) {
            int pz = ((ks * 4 + quad) ^ chl);
            bf16x8 a0 = *reinterpret_cast<const bf16x8*>(
                &vb[(((2 * w)     * 2 + (l15 >> 3)) * 64 + chl * 8 + pz) * 8]);
            bf16x8 a1 = *reinterpret_cast<const bf16x8*>(
                &vb[(((2 * w + 1) * 2 + (l15 >> 3)) * 64 + chl * 8 + pz) * 8]);
            const int ob = (ks * 4 + quad) * 64;
            bf16x8 p0 = *reinterpret_cast<const bf16x8*>(&pr[(ob +  0 + l15) * 8]);
            bf16x8 p1 = *reinterpret_cast<const bf16x8*>(&pr[(ob + 16 + l15) * 8]);
            bf16x8 p2 = *reinterpret_cast<const bf16x8*>(&pr[(ob + 32 + l15) * 8]);
            bf16x8 p3 = *reinterpret_cast<const bf16x8*>(&pr[(ob + 48 + l15) * 8]);
            acc[0][0] = MFMA(a0, p0, acc[0][0]);
            acc[0][1] = MFMA(a0, p1, acc[0][1]);
            acc[0][2] = MFMA(a0, p2, acc[0][2]);
            acc[0][3] = MFMA(a0, p3, acc[0][3]);
            acc[1][0] = MFMA(a1, p0, acc[1][0]);
            acc[1][1] = MFMA(a1, p1, acc[1][1]);
            acc[1][2] = MFMA(a1, p2, acc[1][2]);
            acc[1][3] = MFMA(a1, p3, acc[1][3]);
        }
    };

    for (int i = 0; i < KT_PER; i += 2) {
        iter(kt0 + i, kA, kB, 0);
        if (i + 1 < KT_PER) iter(kt0 + i + 1, kB, kA, 1);
    }

    // epilogue: quad-reduce lp, cross-wave l reduction via LDS scratch
    __syncthreads();
    float* lsh = reinterpret_cast<float*>(&p_lds[0][0]);   // 256 floats
    float lt[4];
#pragma unroll
    for (int ni = 0; ni < 4; ++ni) {
        float ps = lp[ni];
        ps += __shfl_xor(ps, 16, 64);
        ps += __shfl_xor(ps, 32, 64);
        lt[ni] = ps;
    }
    if (quad == 0) {
#pragma unroll
        for (int ni = 0; ni < 4; ++ni)
            lsh[w * 64 + ni * 16 + l15] = lt[ni];
    }
    __syncthreads();

    // write av partials: av_part[sp][n][c] fp32
    float* dst = av_part + (size_t)sp * 1024000;
    for (int mi = 0; mi < 2; ++mi)
        for (int ni = 0; ni < 4; ++ni) {
            int n  = n0q + ni * 16 + l15;
            int ch = (2 * w + mi) * 16 + quad * 4;
            *reinterpret_cast<f32x4*>(&dst[n * 128 + ch]) = acc[mi][ni];
        }
    if (t < 64)
        l_part[sp * N_POS + n0q + t] =
            lsh[t] + lsh[64 + t] + lsh[128 + t] + lsh[192 + t];
}

// ---------------------------------------------------------------------------
// Kernel C: split-K reduce + normalize (fp32, in LDS) fused with
// y = wa @ av + ba (MFMA) + BN stats.  grid 250, n-tile 32.
// (round-1 fused version -- measured best; the reduce/proj split cost +7 us.)
// ---------------------------------------------------------------------------
__global__ __launch_bounds__(256) void proj_out_kernel(
    const float* __restrict__ av_part, const float* __restrict__ l_part,
    const float* __restrict__ wa, const float* __restrict__ ba,
    float* __restrict__ y_ws, float* __restrict__ bn_sum, float* __restrict__ bn_sumsq)
{
    __shared__ __bf16 b_lds[4096];   // 32n x 128c fragment-packed, swizzled

    const int t    = threadIdx.x;
    const int n0   = blockIdx.x * 32;
    const int lane = t & 63;
    const int w    = t >> 6;
    const int l15  = lane & 15;
    const int quad = lane >> 4;

    // build normalized B tile: 512 c-octets, 2 per thread (coalesced reads)
    for (int r = 0; r < 2; ++r) {
        int g = r * 256 + t;
        int n = g >> 4, oc = g & 15;
        float l = 0.f;
#pragma unroll
        for (int s = 0; s < KSPLIT; ++s) l += l_part[s * N_POS + n0 + n];
        float4 a0 = make_float4(0.f, 0.f, 0.f, 0.f);
        float4 a1 = make_float4(0.f, 0.f, 0.f, 0.f);
#pragma unroll
        for (int s = 0; s < KSPLIT; ++s) {
            const float* p = av_part + (size_t)s * 1024000 + (n0 + n) * 128 + oc * 8;
            float4 u = *reinterpret_cast<const float4*>(p);
            float4 v = *reinterpret_cast<const float4*>(p + 4);
            a0.x += u.x; a0.y += u.y; a0.z += u.z; a0.w += u.w;
            a1.x += v.x; a1.y += v.y; a1.z += v.z; a1.w += v.w;
        }
        float inv = 1.f / l;
        union { int4 iv; __bf16 b[8]; } u;
        u.b[0]=(__bf16)(a0.x*inv); u.b[1]=(__bf16)(a0.y*inv);
        u.b[2]=(__bf16)(a0.z*inv); u.b[3]=(__bf16)(a0.w*inv);
        u.b[4]=(__bf16)(a1.x*inv); u.b[5]=(__bf16)(a1.y*inv);
        u.b[6]=(__bf16)(a1.z*inv); u.b[7]=(__bf16)(a1.w*inv);
        int A = (n >> 4) * 16 + oc;
        int slot = (n & 15) ^ (oc & 7);
        *reinterpret_cast<int4*>(&b_lds[(A * 16 + slot) * 8]) = u.iv;
    }

    // A-frags: wa rows for mtiles {2w, 2w+1}
    bf16x8 aw[2][4];
    f32x4  acc[2][2];
    for (int mi = 0; mi < 2; ++mi) {
        int mt = 2 * w + mi;
        const float* wrow = wa + (mt * 16 + l15) * 128;
        for (int ks = 0; ks < 4; ++ks) {
            float4 f0 = *reinterpret_cast<const float4*>(wrow + ks * 32 + quad * 8);
            float4 f1 = *reinterpret_cast<const float4*>(wrow + ks * 32 + quad * 8 + 4);
            bf16x8 a;
            a[0]=(__bf16)f0.x; a[1]=(__bf16)f0.y; a[2]=(__bf16)f0.z; a[3]=(__bf16)f0.w;
            a[4]=(__bf16)f1.x; a[5]=(__bf16)f1.y; a[6]=(__bf16)f1.z; a[7]=(__bf16)f1.w;
            aw[mi][ks] = a;
        }
        for (int ni = 0; ni < 2; ++ni) {
            acc[mi][ni][0] = ba[mt * 16 + quad * 4 + 0];
            acc[mi][ni][1] = ba[mt * 16 + quad * 4 + 1];
            acc[mi][ni][2] = ba[mt * 16 + quad * 4 + 2];
            acc[mi][ni][3] = ba[mt * 16 + quad * 4 + 3];
        }
    }
    __syncthreads();

    for (int ks = 0; ks < 4; ++ks) {
        int oc = ks * 4 + quad;
        int slot = l15 ^ (oc & 7);
        bf16x8 b0 = *reinterpret_cast<const bf16x8*>(&b_lds[((0  + oc) * 16 + slot) * 8]);
        bf16x8 b1 = *reinterpret_cast<const bf16x8*>(&b_lds[((16 + oc) * 16 + slot) * 8]);
        for (int mi = 0; mi < 2; ++mi) {
            acc[mi][0] = MFMA(aw[mi][ks], b0, acc[mi][0]);
            acc[mi][1] = MFMA(aw[mi][ks], b1, acc[mi][1]);
        }
    }

    // y writes [c][n] + BN partial stats
    for (int mi = 0; mi < 2; ++mi) {
        for (int r = 0; r < 4; ++r) {
            int ch = (2 * w + mi) * 16 + quad * 4 + r;
            float v0 = acc[mi][0][r];
            float v1 = acc[mi][1][r];
            y_ws[ch * N_POS + n0 + 0  + l15] = v0;
            y_ws[ch * N_POS + n0 + 16 + l15] = v1;
            float s1 = v0 + v1;
            float s2 = v0 * v0 + v1 * v1;
#pragma unroll
            for (int off = 8; off >= 1; off >>= 1) {
                s1 += __shfl_xor(s1, off, 64);
                s2 += __shfl_xor(s2, off, 64);
            }
            if (l15 == 0) {
                atomicAdd(&bn_sum[ch],   s1);
                atomicAdd(&bn_sumsq[ch], s2);
            }
        }
    }
}

// ---------------------------------------------------------------------------
// Kernel D: BatchNorm (training stats) + ReLU + residual. grid 1000, block 256.
// ---------------------------------------------------------------------------
__global__ __launch_bounds__(256) void bn_relu_kernel(
    const float* __restrict__ y_ws, const float* __restrict__ x,
    const float* __restrict__ bn_sum, const float* __restrict__ bn_sumsq,
    const float* __restrict__ bn_w, const float* __restrict__ bn_b,
    float* __restrict__ out)
{
    const int i4 = blockIdx.x * 256 + threadIdx.x;
    const int c  = i4 / 2000;
    const float mean  = bn_sum[c]   * (1.f / 8000.f);
    const float var   = bn_sumsq[c] * (1.f / 8000.f) - mean * mean;
    const float rstd  = rsqrtf(var + 1e-5f);
    const float scale = bn_w[c] * rstd;
    const float shift = bn_b[c] - mean * scale;

    float4 y4 = reinterpret_cast<const float4*>(y_ws)[i4];
    float4 x4 = reinterpret_cast<const float4*>(x)[i4];
    float4 o4;
    o4.x = fmaxf(y4.x * scale + shift, 0.f) + x4.x;
    o4.y = fmaxf(y4.y * scale + shift, 0.f) + x4.y;
    o4.z = fmaxf(y4.z * scale + shift, 0.f) + x4.z;
    o4.w = fmaxf(y4.w * scale + shift, 0.f) + x4.w;
    reinterpret_cast<float4*>(out)[i4] = o4;
}

// ---------------------------------------------------------------------------
extern "C" void kernel_launch(void* const* d_in, const int* in_sizes, int n_in,
                              void* d_out, int out_size, void* d_ws, size_t ws_size,
                              hipStream_t stream)
{
    const float* x    = (const float*)d_in[0];
    const float* wq   = (const float*)d_in[1];
    const float* bq   = (const float*)d_in[2];
    const float* wk   = (const float*)d_in[3];
    const float* bk   = (const float*)d_in[4];
    const float* wv   = (const float*)d_in[5];
    const float* bv   = (const float*)d_in[6];
    const float* wa   = (const float*)d_in[7];
    const float* ba   = (const float*)d_in[8];
    const float* bn_w = (const float*)d_in[9];
    const float* bn_b = (const float*)d_in[10];
    float* out = (float*)d_out;

    char* base = (char*)d_ws;
    // byte layout (~27.3 MB):
    float*  av_part = (float*)base;                    // 20,480,000 B (5 x 8000 x 128 f32)
    __bf16* q_bf    = (__bf16*)(base + 20480000);      //    256,000 B
    __bf16* k_bf    = (__bf16*)(base + 20736000);      //    256,000 B
    __bf16* v_bf    = (__bf16*)(base + 20992000);      //  2,048,000 B
    float*  l_part  = (float*)(base + 23040000);       //    160,000 B
    float*  bn_sum   = (float*)(base + 23200000);      //        512 B
    float*  bn_sumsq = bn_sum + 128;                   //        512 B
    float*  y_ws    = (float*)(base + 23201024);       //  4,096,000 B

    hipMemsetAsync(bn_sum, 0, 1024, stream);
    qkv_kernel<<<250, 256, 0, stream>>>(x, wq, bq, wk, bk, wv, bv, q_bf, k_bf, v_bf);
    attn_kernel<<<QTILES * KSPLIT, 256, 0, stream>>>(q_bf, k_bf, v_bf, av_part, l_part);
    proj_out_kernel<<<250, 256, 0, stream>>>(av_part, l_part, wa, ba, y_ws, bn_sum, bn_sumsq);
    bn_relu_kernel<<<1000, 256, 0, stream>>>(y_ws, x, bn_sum, bn_sumsq, bn_w, bn_b, out);
}